// Round 12
// baseline (1502.869 us; speedup 1.0000x reference)
//
#include <hip/hip_runtime.h>
#include <stdint.h>

#define T_TOK 4096
#define DIN   2048
#define DQ    2048
#define DKV   2048
#define NOUT  (DQ + 2*DKV)         /* 6144 */
#define NA    4
#define RLORA 16
#define BM    256
#define BN    256
#define MPAD  (T_TOK + NA*BM)      /* 5120 */
#define MTILES (MPAD/BM)           /* 20 */
#define KX    (DIN + 64)           /* 2112 */
#define NKT   (KX/32)              /* 66 K-tiles of 32 */
#define KSPLIT 16
#define NTBLK (NOUT/BN)            /* 24 */
#define NWG   (MTILES*NTBLK)       /* 480 */

typedef unsigned short u16;
typedef __attribute__((ext_vector_type(8))) short short8;
typedef __attribute__((ext_vector_type(8))) u16 u16x8;
typedef __attribute__((ext_vector_type(4))) float f32x4;
typedef __attribute__((ext_vector_type(2))) float f32x2;

__device__ __forceinline__ u16 f2bf(float f) {
  uint32_t u = __float_as_uint(f);
  u = (u + 0x7FFFu + ((u >> 16) & 1u)) >> 16;
  return (u16)u;
}
__device__ __forceinline__ float bf2f(u16 u) {
  return __uint_as_float(((uint32_t)u) << 16);
}

typedef __attribute__((address_space(3))) void lds_void;
typedef __attribute__((address_space(1))) void glb_void;

__device__ __forceinline__ void gl_lds16(const void* g, void* l) {
  __builtin_amdgcn_global_load_lds((const glb_void*)(uintptr_t)g,
                                   (lds_void*)(uint32_t)(uintptr_t)l, 16, 0, 0);
}

// ---------------------------------------------------------------------------
// Kernel 1: stable counting sort of tokens by adapter, padded to BM multiples.
// ---------------------------------------------------------------------------
__global__ void prep_kernel(const int* __restrict__ widx,
                            int* __restrict__ tok,
                            int* __restrict__ tileAdapter) {
  __shared__ int cnt[256][NA];
  __shared__ int total[NA];
  __shared__ int pad_off[NA];
  const int tid = threadIdx.x;
  const int CH = T_TOK / 256;  // 16
  const int base = tid * CH;
  int c[NA] = {0, 0, 0, 0};
  for (int i = 0; i < CH; i++) c[widx[base + i]]++;
  for (int a = 0; a < NA; a++) cnt[tid][a] = c[a];
  __syncthreads();
  if (tid < NA) {
    int s = 0;
    for (int i = 0; i < 256; i++) { int v = cnt[i][tid]; cnt[i][tid] = s; s += v; }
    total[tid] = s;
  }
  __syncthreads();
  if (tid == 0) {
    int off = 0;
    for (int a = 0; a < NA; a++) {
      pad_off[a] = off;
      int ntile = (total[a] + BM - 1) / BM;
      for (int tl = 0; tl < ntile; tl++) tileAdapter[off / BM + tl] = a;
      off += ntile * BM;
    }
    for (int tl = off / BM; tl < MTILES; tl++) tileAdapter[tl] = -1;
  }
  __syncthreads();
  for (int i = tid; i < MPAD; i += 256) tok[i] = -1;
  __syncthreads();
  int myoff[NA];
  for (int a = 0; a < NA; a++) myoff[a] = pad_off[a] + cnt[tid][a];
  for (int i = 0; i < CH; i++) {
    int a = widx[base + i];
    tok[myoff[a]++] = base + i;
  }
}

// ---------------------------------------------------------------------------
// Kernel 2 (fused gather + Xa partials): per (128-row block, 128-col K-slice):
// gather x rows fp32 -> write bf16 Xg slice -> LDS -> rank-48 partials.
// ---------------------------------------------------------------------------
__global__ __launch_bounds__(256) void gatherxa_kernel(
    const float* __restrict__ x, const float* __restrict__ A_qkv,
    const int* __restrict__ tok, const int* __restrict__ tileAdapter,
    u16* __restrict__ Xg, float* __restrict__ Ppart) {
  const int rb = blockIdx.x;           // 0..MPAD/128-1
  const int ks = blockIdx.y;           // 0..15
  const int kb = ks * 128;
  const int tid = threadIdx.x;
  const int ad = tileAdapter[rb >> 1];
  const int a  = ad < 0 ? 0 : ad;

  __shared__ float ldsX[128][66];      // pad 66: 2-way bank (free)
  __shared__ float ldsA[64][52];
  __shared__ int   s_tok[128];

  if (tid < 128) s_tok[tid] = tok[rb * 128 + tid];
  __syncthreads();

  const int rg = tid >> 2;             // 0..63 -> rows 2rg, 2rg+1
  const int jg = tid & 3;
  const int j0 = jg * 12;
  float acc[2][12];
  #pragma unroll
  for (int r = 0; r < 2; r++)
    #pragma unroll
    for (int j = 0; j < 12; j++) acc[r][j] = 0.f;

  for (int kc = 0; kc < 2; kc++) {
    const int kbase = kb + kc * 64;
    for (int i = tid; i < 64 * 48; i += 256) {
      int kk = i / 48, j = i - kk * 48;
      ldsA[kk][j] = A_qkv[((size_t)a * DIN + kbase + kk) * (3 * RLORA) + j];
    }
    #pragma unroll
    for (int i = 0; i < 4; i++) {
      const int c2 = tid + 256 * i;    // 0..1023
      const int row = c2 >> 3;         // 0..127
      const int col8 = (c2 & 7) * 8;   // 0..56
      const int t = s_tok[row];
      f32x4 v0 = {0.f, 0.f, 0.f, 0.f}, v1 = {0.f, 0.f, 0.f, 0.f};
      if (t >= 0) {
        const float* p = x + (size_t)t * DIN + kbase + col8;
        v0 = *(const f32x4*)p;
        v1 = *(const f32x4*)(p + 4);
      }
      u16x8 o;
      o[0] = f2bf(v0[0]); o[1] = f2bf(v0[1]); o[2] = f2bf(v0[2]); o[3] = f2bf(v0[3]);
      o[4] = f2bf(v1[0]); o[5] = f2bf(v1[1]); o[6] = f2bf(v1[2]); o[7] = f2bf(v1[3]);
      *(u16x8*)(Xg + (size_t)(rb * 128 + row) * KX + kbase + col8) = o;
      *(f32x2*)&ldsX[row][col8]     = (f32x2){v0[0], v0[1]};
      *(f32x2*)&ldsX[row][col8 + 2] = (f32x2){v0[2], v0[3]};
      *(f32x2*)&ldsX[row][col8 + 4] = (f32x2){v1[0], v1[1]};
      *(f32x2*)&ldsX[row][col8 + 6] = (f32x2){v1[2], v1[3]};
    }
    __syncthreads();
    for (int kk = 0; kk < 64; kk++) {
      f32x4 a0 = *(const f32x4*)&ldsA[kk][j0];
      f32x4 a1 = *(const f32x4*)&ldsA[kk][j0 + 4];
      f32x4 a2 = *(const f32x4*)&ldsA[kk][j0 + 8];
      float x0 = ldsX[2 * rg][kk];
      float x1 = ldsX[2 * rg + 1][kk];
      #pragma unroll
      for (int c = 0; c < 4; c++) {
        acc[0][c]     += x0 * a0[c];  acc[1][c]     += x1 * a0[c];
        acc[0][4 + c] += x0 * a1[c];  acc[1][4 + c] += x1 * a1[c];
        acc[0][8 + c] += x0 * a2[c];  acc[1][8 + c] += x1 * a2[c];
      }
    }
    __syncthreads();
  }
  #pragma unroll
  for (int r = 0; r < 2; r++)
    #pragma unroll
    for (int j = 0; j < 12; j++)
      Ppart[((size_t)ks * MPAD + rb * 128 + 2 * rg + r) * 48 + j0 + j] = acc[r][j];
}

// ---------------------------------------------------------------------------
// Kernel 3: reduce partials -> bf16 into Xg cols 2048..2111 (j>=48 zero).
// ---------------------------------------------------------------------------
__global__ void xa_reduce_kernel(const float* __restrict__ Ppart,
                                 u16* __restrict__ Xg) {
  const int gid = blockIdx.x * 256 + threadIdx.x;
  const int row = gid >> 6, j = gid & 63;
  float s = 0.f;
  if (j < 48) {
    #pragma unroll
    for (int sp = 0; sp < KSPLIT; sp++)
      s += Ppart[((size_t)sp * MPAD + row) * 48 + j];
  }
  Xg[(size_t)row * KX + DIN + j] = f2bf(s);
}

// ---------------------------------------------------------------------------
// Kernel 4: Weff[a][n][k] = W_base[n][k] + Delta[a][k][n] (bf16, k<2048),
// f32x4-vectorized DW loads, reg-prefetch across adapters.  Blocks with
// blockIdx.x == DIN/64 fill the LoRA slot columns with scattered B.
// ---------------------------------------------------------------------------
__global__ __launch_bounds__(256) void weff2_kernel(
    const float* __restrict__ W_base,
    const float* __restrict__ DW_q, const float* __restrict__ DW_kv,
    const float* __restrict__ B_q,  const float* __restrict__ B_kv,
    u16* __restrict__ Weff) {
  const int tid = threadIdx.x;
  const int n0 = blockIdx.y * 64;

  if (blockIdx.x == DIN / 64) {
    const int a = tid >> 6;
    const int n = n0 + (tid & 63);
    const int seg = n >> 11;   // 0=q, 1=k, 2=v
    u16 vals[64];
    #pragma unroll
    for (int j = 0; j < 64; j++) vals[j] = 0;
    if (seg == 0) {
      const float* Bp = B_q + ((size_t)a * RLORA) * DQ + n;
      #pragma unroll
      for (int r = 0; r < RLORA; r++) vals[r] = f2bf(Bp[(size_t)r * DQ]);
    } else if (seg == 1) {
      const float* Bp = B_kv + ((size_t)a * RLORA) * (2 * DKV) + (n - DQ);
      #pragma unroll
      for (int r = 0; r < RLORA; r++)
        vals[RLORA + r] = f2bf(Bp[(size_t)r * (2 * DKV)]);
    } else {
      const float* Bp = B_kv + ((size_t)a * RLORA) * (2 * DKV) + (n - DQ);
      #pragma unroll
      for (int r = 0; r < RLORA; r++)
        vals[2 * RLORA + r] = f2bf(Bp[(size_t)r * (2 * DKV)]);
    }
    u16* dst = Weff + ((size_t)a * NOUT + n) * KX + DIN;
    #pragma unroll
    for (int v = 0; v < 8; v++) *(u16x8*)(dst + v * 8) = *(u16x8*)(vals + v * 8);
    return;
  }

  const int k0 = blockIdx.x * 64;
  const int k8 = (tid & 7) * 8;
  __shared__ float ldsD[64][65];

  f32x4 wb[2][2];
  #pragma unroll
  for (int h = 0; h < 2; h++) {
    const int nn = h * 32 + (tid >> 3);
    const float* p = W_base + (size_t)(n0 + nn) * DIN + k0 + k8;
    wb[h][0] = *(const f32x4*)p;
    wb[h][1] = *(const f32x4*)(p + 4);
  }

  const int ldD  = (n0 < DQ) ? DQ : 2 * DKV;
  const int ncol = (n0 < DQ) ? n0 : n0 - DQ;
  const float* Dbase = (n0 < DQ) ? (DW_q + ncol) : (DW_kv + ncol);
  const size_t Dstride = (n0 < DQ) ? (size_t)DIN * DQ : (size_t)DIN * (2 * DKV);

  const int lkk  = tid >> 4;        // 0..15
  const int lnn4 = (tid & 15) * 4;  // 0..60

  f32x4 v4[4];
  #pragma unroll
  for (int j = 0; j < 4; j++)
    v4[j] = *(const f32x4*)(Dbase + (size_t)(k0 + lkk + 16 * j) * ldD + lnn4);

  for (int a = 0; a < NA; a++) {
    #pragma unroll
    for (int j = 0; j < 4; j++)
      #pragma unroll
      for (int c = 0; c < 4; c++)
        ldsD[lkk + 16 * j][lnn4 + c] = v4[j][c];
    if (a < NA - 1) {
      const float* Dp = Dbase + (size_t)(a + 1) * Dstride;
      #pragma unroll
      for (int j = 0; j < 4; j++)
        v4[j] = *(const f32x4*)(Dp + (size_t)(k0 + lkk + 16 * j) * ldD + lnn4);
    }
    __syncthreads();
    #pragma unroll
    for (int h = 0; h < 2; h++) {
      const int nn = h * 32 + (tid >> 3);
      u16x8 o;
      #pragma unroll
      for (int j = 0; j < 8; j++)
        o[j] = f2bf(wb[h][j >> 2][j & 3] + ldsD[k8 + j][nn]);
      *(u16x8*)(Weff + ((size_t)a * NOUT + n0 + nn) * KX + k0 + k8) = o;
    }
    __syncthreads();
  }
}

// ---------------------------------------------------------------------------
// Kernel 5: grouped GEMM, 256x256 tile, BK=32, 8 waves (2Mx4N).
// 2 LDS buffers = 64 KB -> 2 blocks/CU; all 480 blocks co-resident (no tail).
// Per tile: WAITV(0); BAR; 12 ds_read + stage t+1; 32 MFMA.  Inter-block
// overlap (m114/m97 mechanism) covers the per-tile drain.
// ---------------------------------------------------------------------------
#define BAR      asm volatile("s_barrier" ::: "memory")
#define WAITV(n) asm volatile("s_waitcnt vmcnt(" #n ")" ::: "memory")

// A bufs: elem b*8192 (16KB each, rows 64B).  B bufs: elem 16384 + b*8192.
#define ST(b, t) { \
  gl_lds16(gAsrc + (size_t)(t) * 32, ldsu + (b)*8192 + tid * 8); \
  gl_lds16(gAsrc + (size_t)128 * KX + (size_t)(t) * 32, \
           ldsu + (b)*8192 + 4096 + tid * 8); \
  gl_lds16(gBsrc + (size_t)(t) * 32, ldsu + 16384 + (b)*8192 + tid * 8); \
  gl_lds16(gBsrc + (size_t)128 * KX + (size_t)(t) * 32, \
           ldsu + 16384 + (b)*8192 + 4096 + tid * 8); }

#define RD(b) { \
  _Pragma("unroll") for (int q = 0; q < 8; ++q) \
    af[q] = *(const short8*)(ldsc + (b)*16384 + (wm*128 + q*16)*64 + laneoff); \
  _Pragma("unroll") for (int r = 0; r < 4; ++r) \
    bfr[r] = *(const short8*)(ldsc + 32768 + (b)*16384 + (wn*64 + r*16)*64 + laneoff); }

#define MM32 { \
  __builtin_amdgcn_s_setprio(1); \
  _Pragma("unroll") for (int q = 0; q < 8; ++q) \
  _Pragma("unroll") for (int r = 0; r < 4; ++r) \
    acc[q][r] = __builtin_amdgcn_mfma_f32_16x16x32_bf16( \
        af[q], bfr[r], acc[q][r], 0, 0, 0); \
  __builtin_amdgcn_s_setprio(0); }

#define TILE(b, t) { WAITV(0); BAR; RD(b); ST(1-(b), (t)+1); MM32; }
#define TILE_N(b)  { WAITV(0); BAR; RD(b); MM32; }

__global__ __launch_bounds__(512, 4) void gemm256_kernel(
    const u16* __restrict__ Xg, const u16* __restrict__ Weff,
    const int* __restrict__ tok, const int* __restrict__ tileAdapter,
    float* __restrict__ out) {
  __shared__ __align__(16) u16 Lds[32768];   // 64 KiB: A[2] | B[2]

  const int bid = blockIdx.x;
  const int wg = (bid & 7) * (NWG / 8) + (bid >> 3);
  const int mt = wg % MTILES, nt = wg / MTILES;
  const int a = tileAdapter[mt];
  if (a < 0) return;
  const int m0 = mt * BM, n0 = nt * BN;

  const int tid = threadIdx.x;
  const int l = tid & 63, w = tid >> 6;
  const int wm = w >> 2, wn = w & 3;
  const int fr = l & 15;
  // read: row fr, 16B chunk (l>>4) ^ ((fr>>1)&3)  [2-way, measured 0-conflict]
  const int laneoff = fr * 64 + ((((l >> 4) ^ ((fr >> 1) & 3))) << 4);

  // staging: thread covers row tid>>2 (and +128), source chunk pre-swizzled
  const int srow = tid >> 2;
  const int scol = (((tid & 3) ^ ((tid >> 3) & 3))) * 8;
  const u16* gAsrc = Xg + (size_t)(m0 + srow) * KX + scol;
  const u16* gBsrc = Weff + ((size_t)a * NOUT + n0 + srow) * KX + scol;

  u16* ldsu = &Lds[0];
  const char* ldsc = (const char*)ldsu;

  f32x4 acc[8][4];
  #pragma unroll
  for (int i = 0; i < 8; i++)
    #pragma unroll
    for (int j = 0; j < 4; j++) acc[i][j] = (f32x4){0.f, 0.f, 0.f, 0.f};

  short8 af[8], bfr[4];

  // prologue: stage tile 0 into buf 0
  ST(0, 0);

  // 66 tiles: 32 pairs (0..63) + tile 64 (stages 65) + tile 65 (no stage)
  for (int p = 0; p < 16; ++p) {
    const int t4 = 4 * p;
    TILE(0, t4 + 0);
    TILE(1, t4 + 1);
    TILE(0, t4 + 2);
    TILE(1, t4 + 3);
  }
  TILE(0, 64);
  TILE_N(1);

  // C-write: scatter rows via tok
  #pragma unroll
  for (int mi = 0; mi < 8; ++mi) {
    const int rb = m0 + wm * 128 + mi * 16 + ((l >> 4) << 2);
    int tt[4];
    #pragma unroll
    for (int reg = 0; reg < 4; ++reg) tt[reg] = tok[rb + reg];
    #pragma unroll
    for (int ni = 0; ni < 4; ++ni) {
      const int col = n0 + wn * 64 + ni * 16 + fr;
      #pragma unroll
      for (int reg = 0; reg < 4; ++reg)
        if (tt[reg] >= 0) out[(size_t)tt[reg] * NOUT + col] = acc[mi][ni][reg];
    }
  }
}

// ---------------------------------------------------------------------------
// Fallback (ws too small): correct fp32 path.
// ---------------------------------------------------------------------------
__global__ void fallback_kernel(const float* __restrict__ x,
                                const float* __restrict__ W_base,
                                const float* __restrict__ A_qkv,
                                const float* __restrict__ B_q,
                                const float* __restrict__ B_kv,
                                const float* __restrict__ DW_q,
                                const float* __restrict__ DW_kv,
                                const int* __restrict__ widx,
                                float* __restrict__ out) {
  const int t = blockIdx.x;
  const int n = blockIdx.y * 256 + threadIdx.x;
  const int a = widx[t];
  __shared__ float xs[DIN];
  __shared__ float ys[3 * RLORA];
  for (int k = threadIdx.x; k < DIN; k += 256) xs[k] = x[(size_t)t * DIN + k];
  __syncthreads();
  if (threadIdx.x < 3 * RLORA) {
    float s = 0.f;
    const float* Ap = A_qkv + (size_t)a * DIN * (3 * RLORA) + threadIdx.x;
    for (int k = 0; k < DIN; k++) s += xs[k] * Ap[(size_t)k * (3 * RLORA)];
    ys[threadIdx.x] = s;
  }
  __syncthreads();
  const float* dcol; int ldD, roff; const float* bcol; int ldB;
  if (n < DQ) {
    dcol = DW_q + (size_t)a * DIN * DQ + n; ldD = DQ; roff = 0;
    bcol = B_q + (size_t)a * RLORA * DQ + n; ldB = DQ;
  } else {
    dcol = DW_kv + (size_t)a * DIN * (2 * DKV) + (n - DQ); ldD = 2 * DKV;
    roff = (n < 2 * DQ) ? RLORA : 2 * RLORA;
    bcol = B_kv + (size_t)a * RLORA * (2 * DKV) + (n - DQ); ldB = 2 * DKV;
  }
  const float* wrow = W_base + (size_t)n * DIN;
  float acc = 0.f;
  for (int k = 0; k < DIN; k++) acc += xs[k] * (wrow[k] + dcol[(size_t)k * ldD]);
  for (int r = 0; r < RLORA; r++) acc += ys[roff + r] * bcol[(size_t)r * ldB];
  out[(size_t)t * NOUT + n] = acc;
}

// ---------------------------------------------------------------------------
extern "C" void kernel_launch(void* const* d_in, const int* in_sizes, int n_in,
                              void* d_out, int out_size, void* d_ws, size_t ws_size,
                              hipStream_t stream) {
  const float* x      = (const float*)d_in[0];
  const float* W_base = (const float*)d_in[1];
  const float* A_qkv  = (const float*)d_in[2];
  const float* B_q    = (const float*)d_in[3];
  const float* B_kv   = (const float*)d_in[4];
  const float* DW_q   = (const float*)d_in[5];
  const float* DW_kv  = (const float*)d_in[6];
  const int*   widx   = (const int*)d_in[7];
  float* out = (float*)d_out;

  const size_t WEFF_BYTES = (size_t)NA * NOUT * KX * sizeof(u16);
  const size_t XG_BYTES   = (size_t)MPAD * KX * sizeof(u16);
  const size_t TOK_BYTES  = (size_t)MPAD * sizeof(int);
  const size_t TILE_BYTES = (size_t)MTILES * sizeof(int);
  const size_t need = WEFF_BYTES + XG_BYTES + TOK_BYTES + TILE_BYTES;

  if (ws_size < need) {
    fallback_kernel<<<dim3(T_TOK, NOUT / 256), 256, 0, stream>>>(
        x, W_base, A_qkv, B_q, B_kv, DW_q, DW_kv, widx, out);
    return;
  }

  char* ws = (char*)d_ws;
  u16* Weff = (u16*)ws;
  u16* Xg   = (u16*)(ws + WEFF_BYTES);
  int* tok  = (int*)(ws + WEFF_BYTES + XG_BYTES);
  int* tileAdapter = tok + MPAD;
  float* Ppart = (float*)ws;   // aliases Weff; consumed before weff2 writes

  prep_kernel<<<1, 256, 0, stream>>>(widx, tok, tileAdapter);
  gatherxa_kernel<<<dim3(MPAD / 128, KSPLIT), 256, 0, stream>>>(
      x, A_qkv, tok, tileAdapter, Xg, Ppart);
  xa_reduce_kernel<<<MPAD * 64 / 256, 256, 0, stream>>>(Ppart, Xg);
  weff2_kernel<<<dim3(DIN / 64 + 1, NOUT / 64), 256, 0, stream>>>(
      W_base, DW_q, DW_kv, B_q, B_kv, Weff);
  gemm256_kernel<<<dim3(NWG), 512, 0, stream>>>(
      Xg, Weff, tok, tileAdapter, out);
}

// Round 13
// 242.380 us; speedup vs baseline: 6.2005x; 6.2005x over previous
//
#include <hip/hip_runtime.h>
#include <stdint.h>

#define T_TOK 4096
#define DIN   2048
#define DQ    2048
#define DKV   2048
#define NOUT  (DQ + 2*DKV)         /* 6144 */
#define NA    4
#define RLORA 16
#define BM    256
#define BN    256
#define MPAD  (T_TOK + NA*BM)      /* 5120 */
#define MTILES (MPAD/BM)           /* 20 */
#define KX    (DIN + 64)           /* 2112 = 33*64 */
#define KSPLIT 16
#define NTBLK (NOUT/BN)            /* 24 */
#define NWG   (MTILES*NTBLK)       /* 480 */

typedef unsigned short u16;
typedef __attribute__((ext_vector_type(8))) short short8;
typedef __attribute__((ext_vector_type(8))) u16 u16x8;
typedef __attribute__((ext_vector_type(4))) float f32x4;
typedef __attribute__((ext_vector_type(2))) float f32x2;

__device__ __forceinline__ u16 f2bf(float f) {
  uint32_t u = __float_as_uint(f);
  u = (u + 0x7FFFu + ((u >> 16) & 1u)) >> 16;
  return (u16)u;
}
__device__ __forceinline__ float bf2f(u16 u) {
  return __uint_as_float(((uint32_t)u) << 16);
}

typedef __attribute__((address_space(3))) void lds_void;
typedef __attribute__((address_space(1))) void glb_void;

__device__ __forceinline__ void gl_lds16(const void* g, void* l) {
  __builtin_amdgcn_global_load_lds((const glb_void*)(uintptr_t)g,
                                   (lds_void*)(uint32_t)(uintptr_t)l, 16, 0, 0);
}

// ---------------------------------------------------------------------------
// Kernel 1: stable counting sort of tokens by adapter, padded to BM multiples.
// ---------------------------------------------------------------------------
__global__ void prep_kernel(const int* __restrict__ widx,
                            int* __restrict__ tok,
                            int* __restrict__ tileAdapter) {
  __shared__ int cnt[256][NA];
  __shared__ int total[NA];
  __shared__ int pad_off[NA];
  const int tid = threadIdx.x;
  const int CH = T_TOK / 256;  // 16
  const int base = tid * CH;
  int c[NA] = {0, 0, 0, 0};
  for (int i = 0; i < CH; i++) c[widx[base + i]]++;
  for (int a = 0; a < NA; a++) cnt[tid][a] = c[a];
  __syncthreads();
  if (tid < NA) {
    int s = 0;
    for (int i = 0; i < 256; i++) { int v = cnt[i][tid]; cnt[i][tid] = s; s += v; }
    total[tid] = s;
  }
  __syncthreads();
  if (tid == 0) {
    int off = 0;
    for (int a = 0; a < NA; a++) {
      pad_off[a] = off;
      int ntile = (total[a] + BM - 1) / BM;
      for (int tl = 0; tl < ntile; tl++) tileAdapter[off / BM + tl] = a;
      off += ntile * BM;
    }
    for (int tl = off / BM; tl < MTILES; tl++) tileAdapter[tl] = -1;
  }
  __syncthreads();
  for (int i = tid; i < MPAD; i += 256) tok[i] = -1;
  __syncthreads();
  int myoff[NA];
  for (int a = 0; a < NA; a++) myoff[a] = pad_off[a] + cnt[tid][a];
  for (int i = 0; i < CH; i++) {
    int a = widx[base + i];
    tok[myoff[a]++] = base + i;
  }
}

// ---------------------------------------------------------------------------
// Kernel 2 (fused gather + Xa partials): per (128-row block, 128-col K-slice):
// gather x rows fp32 -> write bf16 Xg slice -> LDS -> rank-48 partials.
// ---------------------------------------------------------------------------
__global__ __launch_bounds__(256) void gatherxa_kernel(
    const float* __restrict__ x, const float* __restrict__ A_qkv,
    const int* __restrict__ tok, const int* __restrict__ tileAdapter,
    u16* __restrict__ Xg, float* __restrict__ Ppart) {
  const int rb = blockIdx.x;           // 0..MPAD/128-1
  const int ks = blockIdx.y;           // 0..15
  const int kb = ks * 128;
  const int tid = threadIdx.x;
  const int ad = tileAdapter[rb >> 1];
  const int a  = ad < 0 ? 0 : ad;

  __shared__ float ldsX[128][66];      // pad 66: 2-way bank (free)
  __shared__ float ldsA[64][52];
  __shared__ int   s_tok[128];

  if (tid < 128) s_tok[tid] = tok[rb * 128 + tid];
  __syncthreads();

  const int rg = tid >> 2;             // 0..63 -> rows 2rg, 2rg+1
  const int jg = tid & 3;
  const int j0 = jg * 12;
  float acc[2][12];
  #pragma unroll
  for (int r = 0; r < 2; r++)
    #pragma unroll
    for (int j = 0; j < 12; j++) acc[r][j] = 0.f;

  for (int kc = 0; kc < 2; kc++) {
    const int kbase = kb + kc * 64;
    for (int i = tid; i < 64 * 48; i += 256) {
      int kk = i / 48, j = i - kk * 48;
      ldsA[kk][j] = A_qkv[((size_t)a * DIN + kbase + kk) * (3 * RLORA) + j];
    }
    #pragma unroll
    for (int i = 0; i < 4; i++) {
      const int c2 = tid + 256 * i;    // 0..1023
      const int row = c2 >> 3;         // 0..127
      const int col8 = (c2 & 7) * 8;   // 0..56
      const int t = s_tok[row];
      f32x4 v0 = {0.f, 0.f, 0.f, 0.f}, v1 = {0.f, 0.f, 0.f, 0.f};
      if (t >= 0) {
        const float* p = x + (size_t)t * DIN + kbase + col8;
        v0 = *(const f32x4*)p;
        v1 = *(const f32x4*)(p + 4);
      }
      u16x8 o;
      o[0] = f2bf(v0[0]); o[1] = f2bf(v0[1]); o[2] = f2bf(v0[2]); o[3] = f2bf(v0[3]);
      o[4] = f2bf(v1[0]); o[5] = f2bf(v1[1]); o[6] = f2bf(v1[2]); o[7] = f2bf(v1[3]);
      *(u16x8*)(Xg + (size_t)(rb * 128 + row) * KX + kbase + col8) = o;
      *(f32x2*)&ldsX[row][col8]     = (f32x2){v0[0], v0[1]};
      *(f32x2*)&ldsX[row][col8 + 2] = (f32x2){v0[2], v0[3]};
      *(f32x2*)&ldsX[row][col8 + 4] = (f32x2){v1[0], v1[1]};
      *(f32x2*)&ldsX[row][col8 + 6] = (f32x2){v1[2], v1[3]};
    }
    __syncthreads();
    for (int kk = 0; kk < 64; kk++) {
      f32x4 a0 = *(const f32x4*)&ldsA[kk][j0];
      f32x4 a1 = *(const f32x4*)&ldsA[kk][j0 + 4];
      f32x4 a2 = *(const f32x4*)&ldsA[kk][j0 + 8];
      float x0 = ldsX[2 * rg][kk];
      float x1 = ldsX[2 * rg + 1][kk];
      #pragma unroll
      for (int c = 0; c < 4; c++) {
        acc[0][c]     += x0 * a0[c];  acc[1][c]     += x1 * a0[c];
        acc[0][4 + c] += x0 * a1[c];  acc[1][4 + c] += x1 * a1[c];
        acc[0][8 + c] += x0 * a2[c];  acc[1][8 + c] += x1 * a2[c];
      }
    }
    __syncthreads();
  }
  #pragma unroll
  for (int r = 0; r < 2; r++)
    #pragma unroll
    for (int j = 0; j < 12; j++)
      Ppart[((size_t)ks * MPAD + rb * 128 + 2 * rg + r) * 48 + j0 + j] = acc[r][j];
}

// ---------------------------------------------------------------------------
// Kernel 3: reduce partials -> bf16 into Xg cols 2048..2111 (j>=48 zero).
// ---------------------------------------------------------------------------
__global__ void xa_reduce_kernel(const float* __restrict__ Ppart,
                                 u16* __restrict__ Xg) {
  const int gid = blockIdx.x * 256 + threadIdx.x;
  const int row = gid >> 6, j = gid & 63;
  float s = 0.f;
  if (j < 48) {
    #pragma unroll
    for (int sp = 0; sp < KSPLIT; sp++)
      s += Ppart[((size_t)sp * MPAD + row) * 48 + j];
  }
  Xg[(size_t)row * KX + DIN + j] = f2bf(s);
}

// ---------------------------------------------------------------------------
// Kernel 4: Weff[a][n][k] = W_base[n][k] + Delta[a][k][n] (bf16, k<2048),
// f32x4-vectorized DW loads, reg-prefetch across adapters.  Blocks with
// blockIdx.x == DIN/64 fill the LoRA slot columns with scattered B.
// ---------------------------------------------------------------------------
__global__ __launch_bounds__(256) void weff2_kernel(
    const float* __restrict__ W_base,
    const float* __restrict__ DW_q, const float* __restrict__ DW_kv,
    const float* __restrict__ B_q,  const float* __restrict__ B_kv,
    u16* __restrict__ Weff) {
  const int tid = threadIdx.x;
  const int n0 = blockIdx.y * 64;

  if (blockIdx.x == DIN / 64) {
    const int a = tid >> 6;
    const int n = n0 + (tid & 63);
    const int seg = n >> 11;   // 0=q, 1=k, 2=v
    u16 vals[64];
    #pragma unroll
    for (int j = 0; j < 64; j++) vals[j] = 0;
    if (seg == 0) {
      const float* Bp = B_q + ((size_t)a * RLORA) * DQ + n;
      #pragma unroll
      for (int r = 0; r < RLORA; r++) vals[r] = f2bf(Bp[(size_t)r * DQ]);
    } else if (seg == 1) {
      const float* Bp = B_kv + ((size_t)a * RLORA) * (2 * DKV) + (n - DQ);
      #pragma unroll
      for (int r = 0; r < RLORA; r++)
        vals[RLORA + r] = f2bf(Bp[(size_t)r * (2 * DKV)]);
    } else {
      const float* Bp = B_kv + ((size_t)a * RLORA) * (2 * DKV) + (n - DQ);
      #pragma unroll
      for (int r = 0; r < RLORA; r++)
        vals[2 * RLORA + r] = f2bf(Bp[(size_t)r * (2 * DKV)]);
    }
    u16* dst = Weff + ((size_t)a * NOUT + n) * KX + DIN;
    #pragma unroll
    for (int v = 0; v < 8; v++) *(u16x8*)(dst + v * 8) = *(u16x8*)(vals + v * 8);
    return;
  }

  const int k0 = blockIdx.x * 64;
  const int k8 = (tid & 7) * 8;
  __shared__ float ldsD[64][65];

  f32x4 wb[2][2];
  #pragma unroll
  for (int h = 0; h < 2; h++) {
    const int nn = h * 32 + (tid >> 3);
    const float* p = W_base + (size_t)(n0 + nn) * DIN + k0 + k8;
    wb[h][0] = *(const f32x4*)p;
    wb[h][1] = *(const f32x4*)(p + 4);
  }

  const int ldD  = (n0 < DQ) ? DQ : 2 * DKV;
  const int ncol = (n0 < DQ) ? n0 : n0 - DQ;
  const float* Dbase = (n0 < DQ) ? (DW_q + ncol) : (DW_kv + ncol);
  const size_t Dstride = (n0 < DQ) ? (size_t)DIN * DQ : (size_t)DIN * (2 * DKV);

  const int lkk  = tid >> 4;        // 0..15
  const int lnn4 = (tid & 15) * 4;  // 0..60

  f32x4 v4[4];
  #pragma unroll
  for (int j = 0; j < 4; j++)
    v4[j] = *(const f32x4*)(Dbase + (size_t)(k0 + lkk + 16 * j) * ldD + lnn4);

  for (int a = 0; a < NA; a++) {
    #pragma unroll
    for (int j = 0; j < 4; j++)
      #pragma unroll
      for (int c = 0; c < 4; c++)
        ldsD[lkk + 16 * j][lnn4 + c] = v4[j][c];
    if (a < NA - 1) {
      const float* Dp = Dbase + (size_t)(a + 1) * Dstride;
      #pragma unroll
      for (int j = 0; j < 4; j++)
        v4[j] = *(const f32x4*)(Dp + (size_t)(k0 + lkk + 16 * j) * ldD + lnn4);
    }
    __syncthreads();
    #pragma unroll
    for (int h = 0; h < 2; h++) {
      const int nn = h * 32 + (tid >> 3);
      u16x8 o;
      #pragma unroll
      for (int j = 0; j < 8; j++)
        o[j] = f2bf(wb[h][j >> 2][j & 3] + ldsD[k8 + j][nn]);
      *(u16x8*)(Weff + ((size_t)a * NOUT + n0 + nn) * KX + k0 + k8) = o;
    }
    __syncthreads();
  }
}

// ---------------------------------------------------------------------------
// Kernel 5: grouped GEMM, 256x256 tile, BK=64, 8 waves (2Mx4N), 4-phase/K-tile
// schedule (best measured) + lgkmcnt(8) throttle.  vmcnt(4) once per K-tile.
// ---------------------------------------------------------------------------
#define BAR      asm volatile("s_barrier" ::: "memory")
#define WAITV(n) asm volatile("s_waitcnt vmcnt(" #n ")" ::: "memory")
#define LGKM8    asm volatile("s_waitcnt lgkmcnt(8)" ::: "memory")

#define RD_A(db, mh) { \
  _Pragma("unroll") for (int q = 0; q < 4; ++q) { \
    const char* rp = ldsc + (db)*32768 + (wm*128 + (mh)*64 + q*16 + fr)*128; \
    af[q][0] = *(const short8*)(rp + ck0); \
    af[q][1] = *(const short8*)(rp + ck1); } }

#define RD_B(db, nh, bfv) { \
  _Pragma("unroll") for (int q = 0; q < 2; ++q) { \
    const char* rp = ldsc + 65536 + (db)*32768 + ((nh)*128 + wn*32 + q*16 + fr)*128; \
    bfv[q][0] = *(const short8*)(rp + ck0); \
    bfv[q][1] = *(const short8*)(rp + ck1); } }

#define ST_A(db, mh, t) { \
  gl_lds16(gAsrc + (size_t)((mh)*64)*KX + (size_t)(t)*64, \
           ldsu + (db)*16384 + ((mh)*64*64) + stid); \
  gl_lds16(gAsrc + (size_t)(128 + (mh)*64)*KX + (size_t)(t)*64, \
           ldsu + (db)*16384 + ((128 + (mh)*64)*64) + stid); }

#define ST_B(db, nh, t) { \
  gl_lds16(gBsrc + (size_t)((nh)*32)*KX + (size_t)(t)*64, \
           ldsu + 32768 + (db)*16384 + ((nh)*128*64) + stid); \
  gl_lds16(gBsrc + (size_t)(128 + (nh)*32)*KX + (size_t)(t)*64, \
           ldsu + 32768 + (db)*16384 + (((nh)*128 + 64)*64) + stid); }

#define MM(mh, nh, bfv) { \
  __builtin_amdgcn_s_setprio(1); \
  _Pragma("unroll") for (int q = 0; q < 4; ++q) \
  _Pragma("unroll") for (int r = 0; r < 2; ++r) { \
    acc[(mh)*4+q][(nh)*2+r] = __builtin_amdgcn_mfma_f32_16x16x32_bf16( \
        af[q][0], bfv[r][0], acc[(mh)*4+q][(nh)*2+r], 0, 0, 0); \
    acc[(mh)*4+q][(nh)*2+r] = __builtin_amdgcn_mfma_f32_16x16x32_bf16( \
        af[q][1], bfv[r][1], acc[(mh)*4+q][(nh)*2+r], 0, 0, 0); } \
  __builtin_amdgcn_s_setprio(0); }

#define KT_STD(db, t) { \
  RD_A(db, 0); RD_B(db, 0, bf0); ST_A(1-(db), 1, (t)+1); LGKM8; BAR; MM(0, 0, bf0); BAR; \
  RD_B(db, 1, bf1);              ST_B(1-(db), 0, (t)+1); BAR; MM(0, 1, bf1); BAR; \
  RD_A(db, 1);                   ST_A(db, 0, (t)+2);     BAR; MM(1, 1, bf1); BAR; \
  ST_B(db, 1, (t)+2); WAITV(4);                          BAR; MM(1, 0, bf0); BAR; }

#define KT_T31(db, t) { \
  RD_A(db, 0); RD_B(db, 0, bf0); ST_A(1-(db), 1, (t)+1); LGKM8; BAR; MM(0, 0, bf0); BAR; \
  RD_B(db, 1, bf1);              ST_B(1-(db), 0, (t)+1); BAR; MM(0, 1, bf1); BAR; \
  RD_A(db, 1);                                           BAR; MM(1, 1, bf1); BAR; \
  WAITV(0);                                              BAR; MM(1, 0, bf0); BAR; }

#define KT_LAST(db) { \
  RD_A(db, 0); RD_B(db, 0, bf0); LGKM8; BAR; MM(0, 0, bf0); BAR; \
  RD_B(db, 1, bf1);              BAR; MM(0, 1, bf1); BAR; \
  RD_A(db, 1);                   BAR; MM(1, 1, bf1); BAR; \
                                 BAR; MM(1, 0, bf0); BAR; }

__global__ __launch_bounds__(512, 2) void gemm256_kernel(
    const u16* __restrict__ Xg, const u16* __restrict__ Weff,
    const int* __restrict__ tok, const int* __restrict__ tileAdapter,
    float* __restrict__ out) {
  __shared__ __align__(16) u16 Lds[65536];   // A[2][256*64] | B[2][256*64]

  const int bid = blockIdx.x;
  const int wg = (bid & 7) * (NWG / 8) + (bid >> 3);
  const int mt = wg % MTILES, nt = wg / MTILES;
  const int a = tileAdapter[mt];
  if (a < 0) return;
  const int m0 = mt * BM, n0 = nt * BN;

  const int tid = threadIdx.x;
  const int l = tid & 63, w = tid >> 6;
  const int wm = w >> 2, wn = w & 3;
  const int fr = l & 15;
  const int kq = l >> 4;
  const int s7 = l & 7;
  const int ck0 = ((kq ^ s7) << 4);
  const int ck1 = (((4 + kq) ^ s7) << 4);

  const int l64 = tid >> 3;
  const int swc = (tid & 7) ^ (l64 & 7);
  const int stid = tid * 8;
  const u16* gAsrc = Xg + (size_t)(m0 + l64) * KX + swc * 8;
  const int nB = ((l64 >> 5) * 64) + (l64 & 31);
  const u16* gBsrc = Weff + ((size_t)a * NOUT + n0 + nB) * KX + swc * 8;

  u16* ldsu = &Lds[0];
  const char* ldsc = (const char*)ldsu;

  f32x4 acc[8][4];
  #pragma unroll
  for (int i = 0; i < 8; i++)
    #pragma unroll
    for (int j = 0; j < 4; j++) acc[i][j] = (f32x4){0.f, 0.f, 0.f, 0.f};

  short8 af[4][2], bf0[2][2], bf1[2][2];

  ST_A(0, 0, 0); ST_B(0, 0, 0); ST_A(0, 1, 0); ST_B(0, 1, 0);
  ST_A(1, 0, 1); ST_B(1, 1, 1);
  WAITV(4);
  BAR;

  for (int p = 0; p < 15; ++p) {
    const int t0 = 2 * p;
    KT_STD(0, t0);
    KT_STD(1, t0 + 1);
  }
  KT_STD(0, 30);
  KT_T31(1, 31);
  KT_LAST(0);

  #pragma unroll
  for (int mi = 0; mi < 8; ++mi) {
    const int rb = m0 + wm * 128 + mi * 16 + ((l >> 4) << 2);
    int tt[4];
    #pragma unroll
    for (int reg = 0; reg < 4; ++reg) tt[reg] = tok[rb + reg];
    #pragma unroll
    for (int ni = 0; ni < 4; ++ni) {
      const int col = n0 + wn * 64 + ni * 16 + fr;
      #pragma unroll
      for (int reg = 0; reg < 4; ++reg)
        if (tt[reg] >= 0) out[(size_t)tt[reg] * NOUT + col] = acc[mi][ni][reg];
    }
  }
}

// ---------------------------------------------------------------------------
// Fallback (ws too small): correct fp32 path.
// ---------------------------------------------------------------------------
__global__ void fallback_kernel(const float* __restrict__ x,
                                const float* __restrict__ W_base,
                                const float* __restrict__ A_qkv,
                                const float* __restrict__ B_q,
                                const float* __restrict__ B_kv,
                                const float* __restrict__ DW_q,
                                const float* __restrict__ DW_kv,
                                const int* __restrict__ widx,
                                float* __restrict__ out) {
  const int t = blockIdx.x;
  const int n = blockIdx.y * 256 + threadIdx.x;
  const int a = widx[t];
  __shared__ float xs[DIN];
  __shared__ float ys[3 * RLORA];
  for (int k = threadIdx.x; k < DIN; k += 256) xs[k] = x[(size_t)t * DIN + k];
  __syncthreads();
  if (threadIdx.x < 3 * RLORA) {
    float s = 0.f;
    const float* Ap = A_qkv + (size_t)a * DIN * (3 * RLORA) + threadIdx.x;
    for (int k = 0; k < DIN; k++) s += xs[k] * Ap[(size_t)k * (3 * RLORA)];
    ys[threadIdx.x] = s;
  }
  __syncthreads();
  const float* dcol; int ldD, roff; const float* bcol; int ldB;
  if (n < DQ) {
    dcol = DW_q + (size_t)a * DIN * DQ + n; ldD = DQ; roff = 0;
    bcol = B_q + (size_t)a * RLORA * DQ + n; ldB = DQ;
  } else {
    dcol = DW_kv + (size_t)a * DIN * (2 * DKV) + (n - DQ); ldD = 2 * DKV;
    roff = (n < 2 * DQ) ? RLORA : 2 * RLORA;
    bcol = B_kv + (size_t)a * RLORA * (2 * DKV) + (n - DQ); ldB = 2 * DKV;
  }
  const float* wrow = W_base + (size_t)n * DIN;
  float acc = 0.f;
  for (int k = 0; k < DIN; k++) acc += xs[k] * (wrow[k] + dcol[(size_t)k * ldD]);
  for (int r = 0; r < RLORA; r++) acc += ys[roff + r] * bcol[(size_t)r * ldB];
  out[(size_t)t * NOUT + n] = acc;
}

// ---------------------------------------------------------------------------
extern "C" void kernel_launch(void* const* d_in, const int* in_sizes, int n_in,
                              void* d_out, int out_size, void* d_ws, size_t ws_size,
                              hipStream_t stream) {
  const float* x      = (const float*)d_in[0];
  const float* W_base = (const float*)d_in[1];
  const float* A_qkv  = (const float*)d_in[2];
  const float* B_q    = (const float*)d_in[3];
  const float* B_kv   = (const float*)d_in[4];
  const float* DW_q   = (const float*)d_in[5];
  const float* DW_kv  = (const float*)d_in[6];
  const int*   widx   = (const int*)d_in[7];
  float* out = (float*)d_out;

  const size_t WEFF_BYTES = (size_t)NA * NOUT * KX * sizeof(u16);
  const size_t XG_BYTES   = (size_t)MPAD * KX * sizeof(u16);
  const size_t TOK_BYTES  = (size_t)MPAD * sizeof(int);
  const size_t TILE_BYTES = (size_t)MTILES * sizeof(int);
  const size_t need = WEFF_BYTES + XG_BYTES + TOK_BYTES + TILE_BYTES;

  if (ws_size < need) {
    fallback_kernel<<<dim3(T_TOK, NOUT / 256), 256, 0, stream>>>(
        x, W_base, A_qkv, B_q, B_kv, DW_q, DW_kv, widx, out);
    return;
  }

  char* ws = (char*)d_ws;
  u16* Weff = (u16*)ws;
  u16* Xg   = (u16*)(ws + WEFF_BYTES);
  int* tok  = (int*)(ws + WEFF_BYTES + XG_BYTES);
  int* tileAdapter = tok + MPAD;
  float* Ppart = (float*)ws;   // aliases Weff; consumed before weff2 writes

  prep_kernel<<<1, 256, 0, stream>>>(widx, tok, tileAdapter);
  gatherxa_kernel<<<dim3(MPAD / 128, KSPLIT), 256, 0, stream>>>(
      x, A_qkv, tok, tileAdapter, Xg, Ppart);
  xa_reduce_kernel<<<MPAD * 64 / 256, 256, 0, stream>>>(Ppart, Xg);
  weff2_kernel<<<dim3(DIN / 64 + 1, NOUT / 64), 256, 0, stream>>>(
      W_base, DW_q, DW_kv, B_q, B_kv, Weff);
  gemm256_kernel<<<dim3(NWG), 512, 0, stream>>>(
      Xg, Weff, tok, tileAdapter, out);
}